// Round 1
// baseline (762.512 us; speedup 1.0000x reference)
//
#include <hip/hip_runtime.h>
#include <math.h>

#define BATCH 2
#define SEQ   2048
#define NH    32
#define HD    64      // P == head dim == state dim n
#define HID   2048
#define CHUNK 256
#define NCH   (SEQ / CHUNK)   // 8

__device__ __forceinline__ float softplusf(float x) {
    return x > 20.f ? x : log1pf(expf(x));
}

// ---------------------------------------------------------------------------
// K1: dt = softplus(hs_ab @ dt_w + dt_b + dt_bias); g_raw = hs_g @ g_w + g_b
// one block per (b,s) row; 256 threads = 32 h * 2 (dt/g) * 4 k-slices
// ---------------------------------------------------------------------------
__global__ __launch_bounds__(256) void k_proj(
    const float* __restrict__ hs_ab, const float* __restrict__ hs_g,
    const float* __restrict__ dt_w, const float* __restrict__ dt_b,
    const float* __restrict__ g_w,  const float* __restrict__ g_b,
    const float* __restrict__ dt_bias,
    float* __restrict__ dt_out, float* __restrict__ g_out)
{
    __shared__ float red[256];
    int r = blockIdx.x;            // b*SEQ + s
    int t = threadIdx.x;
    int h = t & 31;
    int which = (t >> 5) & 1;      // 0 = dt, 1 = g
    int slice = t >> 6;            // 0..3, each 512 k's
    const float* hid = which ? hs_g : hs_ab;
    const float* w   = which ? g_w  : dt_w;
    const float* hrow = hid + (size_t)r * HID + slice * 512;
    const float* wp   = w + (size_t)(slice * 512) * NH + h;
    float sum = 0.f;
    #pragma unroll 4
    for (int k = 0; k < 512; ++k)
        sum += hrow[k] * wp[(size_t)k * NH];
    red[t] = sum;
    __syncthreads();
    if (t < 64) {
        float tot = red[t] + red[t + 64] + red[t + 128] + red[t + 192];
        int hh = t & 31;
        if ((t >> 5) == 0)
            dt_out[(size_t)r * NH + hh] = softplusf(tot + dt_b[hh] + dt_bias[hh]);
        else
            g_out[(size_t)r * NH + hh] = tot + g_b[hh];
    }
}

// ---------------------------------------------------------------------------
// K2: inverse L2 norms of q (-> invC) and k (-> invB) rows, per (b,s,h)
// 4 rows per block, 64 lanes per row (one full wave each)
// ---------------------------------------------------------------------------
__global__ __launch_bounds__(256) void k_norms(
    const float* __restrict__ q, const float* __restrict__ k,
    float* __restrict__ invC, float* __restrict__ invB)
{
    int t = threadIdx.x;
    int lane = t & 63;
    size_t row = (size_t)blockIdx.x * 4 + (t >> 6);  // (b*SEQ+s)*NH + h
    float qv = q[row * 64 + lane];
    float kv = k[row * 64 + lane];
    float sq = qv * qv, sk = kv * kv;
    #pragma unroll
    for (int off = 32; off > 0; off >>= 1) {
        sq += __shfl_down(sq, off);
        sk += __shfl_down(sk, off);
    }
    if (lane == 0) {
        invC[row] = 1.f / fmaxf(sqrtf(sq), 1e-12f);
        invB[row] = 1.f / fmaxf(sqrtf(sk), 1e-12f);
    }
}

// ---------------------------------------------------------------------------
// K3: per (b,c,h): cumsum of dt*A over chunk -> cum_ws; chunk decay -> cd_ws;
//     states[p,n] = sum_l exp(cum_last - cum_l)*dt_l * B[l,n] * x[l,p]
// 256 threads: thread t owns p = t&63, n in [(t>>6)*16, +16)
// ---------------------------------------------------------------------------
__global__ __launch_bounds__(256) void k_chunk_states(
    const float* __restrict__ dt, const float* __restrict__ A_log,
    const float* __restrict__ kst, const float* __restrict__ vst,
    const float* __restrict__ invB,
    float* __restrict__ cum_ws, float* __restrict__ cd_ws,
    float* __restrict__ states)
{
    __shared__ float sCum[CHUNK];
    __shared__ float sW[CHUNK];
    __shared__ float kS[64 * 64];
    __shared__ float vS[64 * 64];
    int idx = blockIdx.x;
    int h = idx & 31;
    int c = (idx >> 5) & 7;
    int b = idx >> 8;
    int t = threadIdx.x;           // == l
    int s0 = c * CHUNK;
    size_t rowbase = (size_t)b * SEQ + s0;
    float dt_l = dt[(rowbase + t) * NH + h];
    float A = -expf(A_log[h]);
    sCum[t] = dt_l * A;
    __syncthreads();
    // Hillis-Steele inclusive scan over 256
    for (int off = 1; off < CHUNK; off <<= 1) {
        float v = (t >= off) ? sCum[t - off] : 0.f;
        __syncthreads();
        sCum[t] += v;
        __syncthreads();
    }
    float cum_l = sCum[t];
    cum_ws[(rowbase + t) * NH + h] = cum_l;
    float cumlast = sCum[CHUNK - 1];
    sW[t] = expf(cumlast - cum_l) * dt_l;
    if (t == 0) cd_ws[((size_t)b * NCH + c) * NH + h] = expf(cumlast);
    __syncthreads();

    float acc[16];
    #pragma unroll
    for (int j = 0; j < 16; ++j) acc[j] = 0.f;
    int p_own = t & 63;
    int nb = (t >> 6) * 16;
    for (int lt = 0; lt < 4; ++lt) {
        #pragma unroll
        for (int i = 0; i < 16; ++i) {
            int ii = t + i * 256;
            int ll = ii >> 6;
            int col = ii & 63;
            size_t grow = (rowbase + lt * 64 + ll) * NH + h;
            kS[ii] = kst[grow * 64 + col] * invB[grow];
            vS[ii] = vst[grow * 64 + col];
        }
        __syncthreads();
        for (int ll = 0; ll < 64; ++ll) {
            float wl = sW[lt * 64 + ll];
            float xv = vS[ll * 64 + p_own] * wl;
            #pragma unroll
            for (int j = 0; j < 16; ++j)
                acc[j] += kS[ll * 64 + nb + j] * xv;
        }
        __syncthreads();
    }
    size_t sbase = ((((size_t)b * NCH + c) * NH + h) * 64 + p_own) * 64 + nb;
    #pragma unroll
    for (int j = 0; j < 16; ++j) states[sbase + j] = acc[j];
}

// ---------------------------------------------------------------------------
// K4: inter-chunk scan over c (8 steps), IN PLACE: states -> H_prev
// one thread per (b,h,p,n)
// ---------------------------------------------------------------------------
__global__ __launch_bounds__(256) void k_scan(
    float* __restrict__ states, const float* __restrict__ cd)
{
    size_t id = (size_t)blockIdx.x * 256 + threadIdx.x;  // ((b*NH+h)*64+p)*64+n
    size_t bh = id >> 12;          // b*NH + h
    size_t pn = id & 4095;
    size_t b = bh >> 5, h = bh & 31;
    float carry = 0.f;
    for (int c = 0; c < NCH; ++c) {
        size_t bch = (b * NCH + c) * NH + h;
        float st = states[bch * 4096 + pn];
        states[bch * 4096 + pn] = carry;      // H_prev for this chunk
        carry = cd[bch] * carry + st;
    }
}

// ---------------------------------------------------------------------------
// K5: per (b,c,h): y[l,p] = intra-chunk causal part + exp(cum_l)*Cm·H_prev
// thread t == l; Cm row + y accumulator in registers; s-tiles of 64 in LDS
// ---------------------------------------------------------------------------
__global__ __launch_bounds__(256) void k_intra(
    const float* __restrict__ qst, const float* __restrict__ kst,
    const float* __restrict__ vst,
    const float* __restrict__ invC, const float* __restrict__ invB,
    const float* __restrict__ dt, const float* __restrict__ cum_ws,
    const float* __restrict__ Hprev,
    float* __restrict__ y_ws)
{
    __shared__ float sCum[CHUNK];
    __shared__ float sDt[CHUNK];
    __shared__ float bS[64 * 64];
    __shared__ float xS[64 * 64];
    int idx = blockIdx.x;
    int h = idx & 31;
    int c = (idx >> 5) & 7;
    int b = idx >> 8;
    int t = threadIdx.x;           // == l
    int s0 = c * CHUNK;
    size_t rowbase = (size_t)b * SEQ + s0;
    size_t myrow = (rowbase + t) * NH + h;
    float cum_l = cum_ws[myrow];
    sCum[t] = cum_l;
    sDt[t] = dt[myrow];
    float cm[64];
    {
        float inv = invC[myrow];
        const float4* qp = (const float4*)(qst + myrow * 64);
        #pragma unroll
        for (int i = 0; i < 16; ++i) {
            float4 v = qp[i];
            cm[i*4+0] = v.x*inv; cm[i*4+1] = v.y*inv;
            cm[i*4+2] = v.z*inv; cm[i*4+3] = v.w*inv;
        }
    }
    float y[64];
    #pragma unroll
    for (int p = 0; p < 64; ++p) y[p] = 0.f;
    __syncthreads();
    for (int stile = 0; stile < 4; ++stile) {
        #pragma unroll
        for (int i = 0; i < 16; ++i) {
            int ii = t + i * 256;
            int ll = ii >> 6;
            int col = ii & 63;
            size_t grow = (rowbase + stile * 64 + ll) * NH + h;
            bS[ii] = kst[grow * 64 + col] * invB[grow];
            xS[ii] = vst[grow * 64 + col];
        }
        __syncthreads();
        int smax = min(64, t - stile * 64 + 1);   // causal: s <= l
        for (int ss = 0; ss < smax; ++ss) {
            int s = stile * 64 + ss;
            float score = 0.f;
            #pragma unroll
            for (int n = 0; n < 64; ++n) score += cm[n] * bS[ss * 64 + n];
            float coef = score * expf(cum_l - sCum[s]) * sDt[s];
            #pragma unroll
            for (int p = 0; p < 64; ++p) y[p] += coef * xS[ss * 64 + p];
        }
        __syncthreads();
    }
    // inter-chunk: y[p] += exp(cum_l) * sum_n Cm[n] * Hprev[p,n]
    {
        size_t hb = (((size_t)b * NCH + c) * NH + h) * 4096;
        #pragma unroll
        for (int i = 0; i < 16; ++i) {
            int ii = t + i * 256;
            bS[ii] = Hprev[hb + ii];
        }
        __syncthreads();
        float el = expf(cum_l);
        for (int p = 0; p < 64; ++p) {
            float dot = 0.f;
            #pragma unroll
            for (int n = 0; n < 64; ++n) dot += cm[n] * bS[p * 64 + n];
            y[p] += el * dot;
        }
    }
    float4* yp = (float4*)(y_ws + myrow * 64);
    #pragma unroll
    for (int i = 0; i < 16; ++i) {
        float4 v; v.x = y[i*4]; v.y = y[i*4+1]; v.z = y[i*4+2]; v.w = y[i*4+3];
        yp[i] = v;
    }
}

// ---------------------------------------------------------------------------
// K6: y * silu(gate) -> RMSNorm(*norm_weight) -> per-head o_proj (+o_b)
// one block per (b,s) row; y read from d_out (written by K5), out in place
// ---------------------------------------------------------------------------
__global__ __launch_bounds__(256) void k_out(
    const float* __restrict__ g_ws,
    const float* __restrict__ norm_w, const float* __restrict__ o_w,
    const float* __restrict__ o_b, float* __restrict__ out)
{
    __shared__ float tY[2048];
    __shared__ float sil[32];
    __shared__ float red[256];
    int r = blockIdx.x;
    int t = threadIdx.x;
    if (t < 32) {
        float g = g_ws[(size_t)r * 32 + t];
        sil[t] = g / (1.f + expf(-g));
    }
    __syncthreads();
    float ssq = 0.f;
    #pragma unroll
    for (int i = 0; i < 8; ++i) {
        int ii = t + i * 256;
        float v = out[(size_t)r * 2048 + ii] * sil[ii >> 6];
        tY[ii] = v;
        ssq += v * v;
    }
    red[t] = ssq;
    __syncthreads();
    for (int off = 128; off > 0; off >>= 1) {
        if (t < off) red[t] += red[t + off];
        __syncthreads();
    }
    float scale = rsqrtf(red[0] / 2048.f + 1e-5f);
    #pragma unroll
    for (int i = 0; i < 8; ++i) {
        int ii = t + i * 256;
        tY[ii] = tY[ii] * scale * norm_w[ii];
    }
    __syncthreads();
    #pragma unroll
    for (int j = 0; j < 8; ++j) {
        int ii = t + j * 256;
        int hh = ii >> 6;
        int q = ii & 63;
        float sum = o_b[hh * 64 + q];
        const float* wrow = o_w + (size_t)hh * 4096 + q;
        #pragma unroll 8
        for (int p = 0; p < 64; ++p)
            sum += tY[hh * 64 + p] * wrow[(size_t)p * 64];
        out[(size_t)r * 2048 + ii] = sum;
    }
}

extern "C" void kernel_launch(void* const* d_in, const int* in_sizes, int n_in,
                              void* d_out, int out_size, void* d_ws, size_t ws_size,
                              hipStream_t stream) {
    const float* hs_ab   = (const float*)d_in[0];
    const float* hs_g    = (const float*)d_in[1];
    const float* qst     = (const float*)d_in[2];
    const float* kst     = (const float*)d_in[3];
    const float* vst     = (const float*)d_in[4];
    const float* dt_w    = (const float*)d_in[5];
    const float* dt_b    = (const float*)d_in[6];
    const float* g_w     = (const float*)d_in[7];
    const float* g_b     = (const float*)d_in[8];
    const float* A_log   = (const float*)d_in[9];
    const float* dt_bias = (const float*)d_in[10];
    const float* norm_w  = (const float*)d_in[11];
    const float* o_w     = (const float*)d_in[12];
    const float* o_b     = (const float*)d_in[13];
    float* out = (float*)d_out;

    float* ws = (float*)d_ws;
    size_t off = 0;
    float* dt_ws  = ws + off; off += (size_t)BATCH * SEQ * NH;
    float* g_ws   = ws + off; off += (size_t)BATCH * SEQ * NH;
    float* invC   = ws + off; off += (size_t)BATCH * SEQ * NH;
    float* invB   = ws + off; off += (size_t)BATCH * SEQ * NH;
    float* cum_ws = ws + off; off += (size_t)BATCH * SEQ * NH;
    float* cd_ws  = ws + off; off += (size_t)BATCH * NCH * NH;
    float* states = ws + off; off += (size_t)BATCH * NCH * NH * 64 * 64;

    k_proj<<<BATCH * SEQ, 256, 0, stream>>>(hs_ab, hs_g, dt_w, dt_b, g_w, g_b,
                                            dt_bias, dt_ws, g_ws);
    k_norms<<<BATCH * SEQ * NH / 4, 256, 0, stream>>>(qst, kst, invC, invB);
    k_chunk_states<<<BATCH * NCH * NH, 256, 0, stream>>>(dt_ws, A_log, kst, vst,
                                                         invB, cum_ws, cd_ws, states);
    k_scan<<<BATCH * NH * 4096 / 256, 256, 0, stream>>>(states, cd_ws);
    // K5 writes y into d_out (same shape), K6 transforms it in place
    k_intra<<<BATCH * NCH * NH, 256, 0, stream>>>(qst, kst, vst, invC, invB,
                                                  dt_ws, cum_ws, states, out);
    k_out<<<BATCH * SEQ, 256, 0, stream>>>(g_ws, norm_w, o_w, o_b, out);
}

// Round 2
// 624.843 us; speedup vs baseline: 1.2203x; 1.2203x over previous
//
#include <hip/hip_runtime.h>
#include <math.h>

#define BATCH 2
#define SEQ   2048
#define NH    32
#define HID   2048
#define CHUNK 256
#define NCH   8
#define NBCH  (BATCH*NCH*NH)   // 512
#define LDP   68               // padded LDS leading dim (16B-aligned, bank-shifted)

__device__ __forceinline__ float softplusf(float x) {
    return x > 20.f ? x : log1pf(expf(x));
}

// ---------------------------------------------------------------------------
// K1: dt_raw = hs_ab @ dt_w + dt_b + dt_bias -> softplus; g_raw = hs_g @ g_w + g_b
// ---------------------------------------------------------------------------
__global__ __launch_bounds__(256) void k_proj(
    const float* __restrict__ hs_ab, const float* __restrict__ hs_g,
    const float* __restrict__ dt_w, const float* __restrict__ dt_b,
    const float* __restrict__ g_w,  const float* __restrict__ g_b,
    const float* __restrict__ dt_bias,
    float* __restrict__ dt_out, float* __restrict__ g_out)
{
    __shared__ float red[256];
    int r = blockIdx.x;            // b*SEQ + s
    int t = threadIdx.x;
    int h = t & 31;
    int which = (t >> 5) & 1;      // 0 = dt, 1 = g
    int slice = t >> 6;            // 0..3, each 512 k's
    const float* hid = which ? hs_g : hs_ab;
    const float* w   = which ? g_w  : dt_w;
    const float* hrow = hid + (size_t)r * HID + slice * 512;
    const float* wp   = w + (size_t)(slice * 512) * NH + h;
    float sum = 0.f;
    #pragma unroll 4
    for (int k = 0; k < 512; ++k)
        sum += hrow[k] * wp[(size_t)k * NH];
    red[t] = sum;
    __syncthreads();
    if (t < 64) {
        float tot = red[t] + red[t + 64] + red[t + 128] + red[t + 192];
        int hh = t & 31;
        if ((t >> 5) == 0)
            dt_out[(size_t)r * NH + hh] = softplusf(tot + dt_b[hh] + dt_bias[hh]);
        else
            g_out[(size_t)r * NH + hh] = tot + g_b[hh];
    }
}

// ---------------------------------------------------------------------------
// K2: inverse L2 norms of q and k rows
// ---------------------------------------------------------------------------
__global__ __launch_bounds__(256) void k_norms(
    const float* __restrict__ q, const float* __restrict__ k,
    float* __restrict__ invC, float* __restrict__ invB)
{
    int t = threadIdx.x;
    int lane = t & 63;
    size_t row = (size_t)blockIdx.x * 4 + (t >> 6);
    float qv = q[row * 64 + lane];
    float kv = k[row * 64 + lane];
    float sq = qv * qv, sk = kv * kv;
    #pragma unroll
    for (int off = 32; off > 0; off >>= 1) {
        sq += __shfl_down(sq, off);
        sk += __shfl_down(sk, off);
    }
    if (lane == 0) {
        invC[row] = 1.f / fmaxf(sqrtf(sq), 1e-12f);
        invB[row] = 1.f / fmaxf(sqrtf(sk), 1e-12f);
    }
}

// ---------------------------------------------------------------------------
// K3: per (b,c,h) cumsum of dt*A; chunk-ordered copies of cum/dt/w; chunk decay
// ---------------------------------------------------------------------------
__global__ __launch_bounds__(256) void k_cumsum(
    const float* __restrict__ dt, const float* __restrict__ A_log,
    float* __restrict__ cumc, float* __restrict__ wvc,
    float* __restrict__ dtc, float* __restrict__ cd)
{
    __shared__ float sC[256];
    int bch = blockIdx.x;
    int h = bch & 31, c = (bch >> 5) & 7, b = bch >> 8;
    int t = threadIdx.x;
    size_t row = ((size_t)b * SEQ + c * CHUNK + t) * NH + h;
    float dt_l = dt[row];
    float A = -expf(A_log[h]);
    sC[t] = dt_l * A;
    __syncthreads();
    for (int off = 1; off < 256; off <<= 1) {
        float v = (t >= off) ? sC[t - off] : 0.f;
        __syncthreads();
        sC[t] += v;
        __syncthreads();
    }
    float cum = sC[t], cl = sC[255];
    size_t o = (size_t)bch * CHUNK + t;
    cumc[o] = cum;
    wvc[o] = expf(cl - cum) * dt_l;
    dtc[o] = dt_l;
    if (t == 255) cd[bch] = expf(cl);
}

// ---------------------------------------------------------------------------
// K4: partial chunk states (l split in 2 halves of 128):
//     sp[bch*2+half][p][n] = sum_{l in half} w_l * B[l,n] * x[l,p]
// outer-product GEMM, 4x4 register tile per thread
// ---------------------------------------------------------------------------
__global__ __launch_bounds__(256) void k_states(
    const float* __restrict__ kst, const float* __restrict__ vst,
    const float* __restrict__ invB, const float* __restrict__ wvc,
    float* __restrict__ sp)
{
    __shared__ float kS[64 * 64];
    __shared__ float xS[64 * 64];
    int blk = blockIdx.x;
    int half = blk & 1, bch = blk >> 1;
    int h = bch & 31, c = (bch >> 5) & 7, b = bch >> 8;
    int t = threadIdx.x;
    size_t rowbase = (size_t)b * SEQ + c * CHUNK + half * 128;
    int pg = (t & 15) * 4, ng = (t >> 4) * 4;
    float acc[4][4];
    #pragma unroll
    for (int i = 0; i < 4; ++i)
        #pragma unroll
        for (int j = 0; j < 4; ++j) acc[i][j] = 0.f;

    for (int tt = 0; tt < 2; ++tt) {
        int r0 = t >> 4;          // 0..15
        int c4 = (t & 15) * 4;
        #pragma unroll
        for (int i = 0; i < 4; ++i) {
            int row = r0 + i * 16;
            size_t grow = (rowbase + tt * 64 + row) * NH + h;
            float w  = wvc[(size_t)bch * CHUNK + half * 128 + tt * 64 + row];
            float ib = invB[grow];
            float4 kv = *(const float4*)(kst + grow * 64 + c4);
            float4 xv = *(const float4*)(vst + grow * 64 + c4);
            *(float4*)(kS + row * 64 + c4) =
                make_float4(kv.x * ib, kv.y * ib, kv.z * ib, kv.w * ib);
            *(float4*)(xS + row * 64 + c4) =
                make_float4(xv.x * w, xv.y * w, xv.z * w, xv.w * w);
        }
        __syncthreads();
        for (int ll = 0; ll < 64; ++ll) {
            float4 x4 = *(const float4*)(xS + ll * 64 + pg);
            float4 k4 = *(const float4*)(kS + ll * 64 + ng);
            acc[0][0] += x4.x * k4.x; acc[0][1] += x4.x * k4.y;
            acc[0][2] += x4.x * k4.z; acc[0][3] += x4.x * k4.w;
            acc[1][0] += x4.y * k4.x; acc[1][1] += x4.y * k4.y;
            acc[1][2] += x4.y * k4.z; acc[1][3] += x4.y * k4.w;
            acc[2][0] += x4.z * k4.x; acc[2][1] += x4.z * k4.y;
            acc[2][2] += x4.z * k4.z; acc[2][3] += x4.z * k4.w;
            acc[3][0] += x4.w * k4.x; acc[3][1] += x4.w * k4.y;
            acc[3][2] += x4.w * k4.z; acc[3][3] += x4.w * k4.w;
        }
        __syncthreads();
    }
    size_t obase = (size_t)blk * 4096;
    #pragma unroll
    for (int i = 0; i < 4; ++i)
        *(float4*)(sp + obase + (pg + i) * 64 + ng) =
            make_float4(acc[i][0], acc[i][1], acc[i][2], acc[i][3]);
}

// ---------------------------------------------------------------------------
// K5: inter-chunk scan (8 steps): sum 2 partials, emit H_prev per chunk
// ---------------------------------------------------------------------------
__global__ __launch_bounds__(256) void k_scan(
    const float* __restrict__ sp, const float* __restrict__ cd,
    float* __restrict__ Hp)
{
    size_t id = (size_t)blockIdx.x * 256 + threadIdx.x;
    size_t bh = id >> 12, pn = id & 4095;
    size_t b = bh >> 5, h = bh & 31;
    float carry = 0.f;
    for (int c = 0; c < NCH; ++c) {
        size_t bch = (b * NCH + c) * NH + h;
        float st = sp[(bch * 2) * 4096 + pn] + sp[(bch * 2 + 1) * 4096 + pn];
        Hp[bch * 4096 + pn] = carry;
        carry = cd[bch] * carry + st;
    }
}

// ---------------------------------------------------------------------------
// K6: intra-chunk causal attention part + H_prev term
// block = (bch, lt): 128 l-rows; thread = (lrow 0..63, q 0..3): rows 2*lrow,
// 2*lrow+1 and p/n-quarter q. Score via quad shuffles.
// ---------------------------------------------------------------------------
__global__ __launch_bounds__(256) void k_intra(
    const float* __restrict__ qst, const float* __restrict__ kst,
    const float* __restrict__ vst,
    const float* __restrict__ invC, const float* __restrict__ invB,
    const float* __restrict__ cumc, const float* __restrict__ dtc,
    const float* __restrict__ Hp,
    float* __restrict__ y_out)
{
    __shared__ float bS[64 * LDP];
    __shared__ float xS[64 * LDP];
    __shared__ float sCumT[64];
    __shared__ float sDtT[64];
    int blk = blockIdx.x;
    int lt = blk & 1, bch = blk >> 1;
    int h = bch & 31, c = (bch >> 5) & 7, b = bch >> 8;
    int t = threadIdx.x;
    int lrow = t >> 2, q = t & 3;
    int l0 = lt * 128 + lrow * 2, l1 = l0 + 1;
    size_t rowbase = (size_t)b * SEQ + c * CHUNK;
    size_t row0 = (rowbase + l0) * NH + h;
    size_t row1 = (rowbase + l1) * NH + h;
    float cum0 = cumc[(size_t)bch * CHUNK + l0];
    float cum1 = cumc[(size_t)bch * CHUNK + l1];

    float cm0[16], cm1[16];
    {
        float i0 = invC[row0], i1 = invC[row1];
        const float4* q0 = (const float4*)(qst + row0 * 64 + q * 16);
        const float4* q1 = (const float4*)(qst + row1 * 64 + q * 16);
        #pragma unroll
        for (int k = 0; k < 4; ++k) {
            float4 a = q0[k], bb = q1[k];
            cm0[k * 4 + 0] = a.x * i0;  cm0[k * 4 + 1] = a.y * i0;
            cm0[k * 4 + 2] = a.z * i0;  cm0[k * 4 + 3] = a.w * i0;
            cm1[k * 4 + 0] = bb.x * i1; cm1[k * 4 + 1] = bb.y * i1;
            cm1[k * 4 + 2] = bb.z * i1; cm1[k * 4 + 3] = bb.w * i1;
        }
    }
    float y0[16], y1[16];
    #pragma unroll
    for (int j = 0; j < 16; ++j) { y0[j] = 0.f; y1[j] = 0.f; }

    int ntile = 2 * lt + 2;
    for (int st = 0; st < ntile; ++st) {
        {   // stage B (scaled) and X tiles, rows st*64..+63
            int r0 = t >> 4, c4 = (t & 15) * 4;
            #pragma unroll
            for (int i = 0; i < 4; ++i) {
                int row = r0 + i * 16;
                size_t grow = (rowbase + st * 64 + row) * NH + h;
                float ib = invB[grow];
                float4 kv = *(const float4*)(kst + grow * 64 + c4);
                float4 xv = *(const float4*)(vst + grow * 64 + c4);
                *(float4*)(bS + row * LDP + c4) =
                    make_float4(kv.x * ib, kv.y * ib, kv.z * ib, kv.w * ib);
                *(float4*)(xS + row * LDP + c4) = xv;
            }
            if (t < 64) {
                sCumT[t] = cumc[(size_t)bch * CHUNK + st * 64 + t];
                sDtT[t]  = dtc[(size_t)bch * CHUNK + st * 64 + t];
            }
        }
        __syncthreads();
        int m1 = min(64, l1 - st * 64 + 1);
        int m0 = min(64, l0 - st * 64 + 1);
        for (int ss = 0; ss < m1; ++ss) {
            const float4* br = (const float4*)(bS + ss * LDP + q * 16);
            float4 b0 = br[0], b1 = br[1], b2 = br[2], b3 = br[3];
            float pA0 = cm0[0]*b0.x + cm0[1]*b0.y + cm0[2]*b0.z + cm0[3]*b0.w
                      + cm0[4]*b1.x + cm0[5]*b1.y + cm0[6]*b1.z + cm0[7]*b1.w;
            float pB0 = cm0[8]*b2.x + cm0[9]*b2.y + cm0[10]*b2.z + cm0[11]*b2.w
                      + cm0[12]*b3.x + cm0[13]*b3.y + cm0[14]*b3.z + cm0[15]*b3.w;
            float pA1 = cm1[0]*b0.x + cm1[1]*b0.y + cm1[2]*b0.z + cm1[3]*b0.w
                      + cm1[4]*b1.x + cm1[5]*b1.y + cm1[6]*b1.z + cm1[7]*b1.w;
            float pB1 = cm1[8]*b2.x + cm1[9]*b2.y + cm1[10]*b2.z + cm1[11]*b2.w
                      + cm1[12]*b3.x + cm1[13]*b3.y + cm1[14]*b3.z + cm1[15]*b3.w;
            float p0 = pA0 + pB0, p1 = pA1 + pB1;
            p0 += __shfl_xor(p0, 1); p0 += __shfl_xor(p0, 2);
            p1 += __shfl_xor(p1, 1); p1 += __shfl_xor(p1, 2);
            float dts = sDtT[ss], cms = sCumT[ss];
            float c0 = (ss < m0) ? p0 * __expf(cum0 - cms) * dts : 0.f;
            float c1 = p1 * __expf(cum1 - cms) * dts;
            const float4* xr = (const float4*)(xS + ss * LDP + q * 16);
            #pragma unroll
            for (int k = 0; k < 4; ++k) {
                float4 x = xr[k];
                y0[k*4+0] += c0 * x.x; y0[k*4+1] += c0 * x.y;
                y0[k*4+2] += c0 * x.z; y0[k*4+3] += c0 * x.w;
                y1[k*4+0] += c1 * x.x; y1[k*4+1] += c1 * x.y;
                y1[k*4+2] += c1 * x.z; y1[k*4+3] += c1 * x.w;
            }
        }
        __syncthreads();
    }

    // ---- H_prev term: y[p] += exp(cum_l) * sum_n Cm[n] * H[p,n] ----
    {
        // stage H transposed into bS: hS[n*LDP + p] = Hp[bch][p*64+n]
        int p = t >> 2;
        const float4* hr = (const float4*)(Hp + (size_t)bch * 4096 + p * 64 + q * 16);
        float4 h0 = hr[0], h1 = hr[1], h2 = hr[2], h3 = hr[3];
        int nb = q * 16;
        bS[(nb+0)*LDP+p]=h0.x;  bS[(nb+1)*LDP+p]=h0.y;  bS[(nb+2)*LDP+p]=h0.z;  bS[(nb+3)*LDP+p]=h0.w;
        bS[(nb+4)*LDP+p]=h1.x;  bS[(nb+5)*LDP+p]=h1.y;  bS[(nb+6)*LDP+p]=h1.z;  bS[(nb+7)*LDP+p]=h1.w;
        bS[(nb+8)*LDP+p]=h2.x;  bS[(nb+9)*LDP+p]=h2.y;  bS[(nb+10)*LDP+p]=h2.z; bS[(nb+11)*LDP+p]=h2.w;
        bS[(nb+12)*LDP+p]=h3.x; bS[(nb+13)*LDP+p]=h3.y; bS[(nb+14)*LDP+p]=h3.z; bS[(nb+15)*LDP+p]=h3.w;
        __syncthreads();
        float el0 = __expf(cum0), el1 = __expf(cum1);
        int lane = t & 63;
        int qb = lane & ~3;
        #pragma unroll
        for (int nq = 0; nq < 4; ++nq) {
            #pragma unroll
            for (int jj = 0; jj < 16; ++jj) {
                int n = nq * 16 + jj;
                float cv0 = __shfl(cm0[jj], qb + nq, 64) * el0;
                float cv1 = __shfl(cm1[jj], qb + nq, 64) * el1;
                const float4* hR = (const float4*)(bS + n * LDP + q * 16);
                #pragma unroll
                for (int k = 0; k < 4; ++k) {
                    float4 hv = hR[k];
                    y0[k*4+0] += cv0 * hv.x; y0[k*4+1] += cv0 * hv.y;
                    y0[k*4+2] += cv0 * hv.z; y0[k*4+3] += cv0 * hv.w;
                    y1[k*4+0] += cv1 * hv.x; y1[k*4+1] += cv1 * hv.y;
                    y1[k*4+2] += cv1 * hv.z; y1[k*4+3] += cv1 * hv.w;
                }
            }
        }
    }

    float4* o0 = (float4*)(y_out + row0 * 64 + q * 16);
    float4* o1 = (float4*)(y_out + row1 * 64 + q * 16);
    #pragma unroll
    for (int k = 0; k < 4; ++k) {
        o0[k] = make_float4(y0[k*4+0], y0[k*4+1], y0[k*4+2], y0[k*4+3]);
        o1[k] = make_float4(y1[k*4+0], y1[k*4+1], y1[k*4+2], y1[k*4+3]);
    }
}

// ---------------------------------------------------------------------------
// K7: y * silu(gate) -> RMSNorm -> per-head o_proj (+o_b), in place on d_out
// ---------------------------------------------------------------------------
__global__ __launch_bounds__(256) void k_out(
    const float* __restrict__ g_ws,
    const float* __restrict__ norm_w, const float* __restrict__ o_w,
    const float* __restrict__ o_b, float* __restrict__ out)
{
    __shared__ float tY[2048];
    __shared__ float sil[32];
    __shared__ float red[256];
    int r = blockIdx.x;
    int t = threadIdx.x;
    if (t < 32) {
        float g = g_ws[(size_t)r * 32 + t];
        sil[t] = g / (1.f + expf(-g));
    }
    __syncthreads();
    float ssq = 0.f;
    #pragma unroll
    for (int i = 0; i < 8; ++i) {
        int ii = t + i * 256;
        float v = out[(size_t)r * 2048 + ii] * sil[ii >> 6];
        tY[ii] = v;
        ssq += v * v;
    }
    red[t] = ssq;
    __syncthreads();
    for (int off = 128; off > 0; off >>= 1) {
        if (t < off) red[t] += red[t + off];
        __syncthreads();
    }
    float scale = rsqrtf(red[0] / 2048.f + 1e-5f);
    #pragma unroll
    for (int i = 0; i < 8; ++i) {
        int ii = t + i * 256;
        tY[ii] = tY[ii] * scale * norm_w[ii];
    }
    __syncthreads();
    #pragma unroll
    for (int j = 0; j < 8; ++j) {
        int ii = t + j * 256;
        int hh = ii >> 6;
        int qq = ii & 63;
        float sum = o_b[hh * 64 + qq];
        const float* wrow = o_w + (size_t)hh * 4096 + qq;
        #pragma unroll 8
        for (int p = 0; p < 64; ++p)
            sum += tY[hh * 64 + p] * wrow[(size_t)p * 64];
        out[(size_t)r * 2048 + ii] = sum;
    }
}

extern "C" void kernel_launch(void* const* d_in, const int* in_sizes, int n_in,
                              void* d_out, int out_size, void* d_ws, size_t ws_size,
                              hipStream_t stream) {
    const float* hs_ab   = (const float*)d_in[0];
    const float* hs_g    = (const float*)d_in[1];
    const float* qst     = (const float*)d_in[2];
    const float* kst     = (const float*)d_in[3];
    const float* vst     = (const float*)d_in[4];
    const float* dt_w    = (const float*)d_in[5];
    const float* dt_b    = (const float*)d_in[6];
    const float* g_w     = (const float*)d_in[7];
    const float* g_b     = (const float*)d_in[8];
    const float* A_log   = (const float*)d_in[9];
    const float* dt_bias = (const float*)d_in[10];
    const float* norm_w  = (const float*)d_in[11];
    const float* o_w     = (const float*)d_in[12];
    const float* o_b     = (const float*)d_in[13];
    float* out = (float*)d_out;

    float* ws = (float*)d_ws;
    size_t off = 0;
    float* dt_ws  = ws + off; off += (size_t)BATCH * SEQ * NH;   // 131072
    float* g_ws   = ws + off; off += (size_t)BATCH * SEQ * NH;
    float* invC   = ws + off; off += (size_t)BATCH * SEQ * NH;
    float* invB   = ws + off; off += (size_t)BATCH * SEQ * NH;
    float* cumc   = ws + off; off += (size_t)NBCH * CHUNK;
    float* wvc    = ws + off; off += (size_t)NBCH * CHUNK;
    float* dtc    = ws + off; off += (size_t)NBCH * CHUNK;
    float* cd_ws  = ws + off; off += (size_t)NBCH;
    float* sp     = ws + off; off += (size_t)NBCH * 2 * 4096;    // 16.8 MB
    float* Hp     = ws + off; off += (size_t)NBCH * 4096;        // 8.4 MB

    k_proj<<<BATCH * SEQ, 256, 0, stream>>>(hs_ab, hs_g, dt_w, dt_b, g_w, g_b,
                                            dt_bias, dt_ws, g_ws);
    k_norms<<<BATCH * SEQ * NH / 4, 256, 0, stream>>>(qst, kst, invC, invB);
    k_cumsum<<<NBCH, 256, 0, stream>>>(dt_ws, A_log, cumc, wvc, dtc, cd_ws);
    k_states<<<NBCH * 2, 256, 0, stream>>>(kst, vst, invB, wvc, sp);
    k_scan<<<BATCH * NH * 4096 / 256, 256, 0, stream>>>(sp, cd_ws, Hp);
    k_intra<<<NBCH * 2, 256, 0, stream>>>(qst, kst, vst, invC, invB,
                                          cumc, dtc, Hp, out);
    k_out<<<BATCH * SEQ, 256, 0, stream>>>(g_ws, norm_w, o_w, o_b, out);
}

// Round 3
// 406.951 us; speedup vs baseline: 1.8737x; 1.5354x over previous
//
#include <hip/hip_runtime.h>
#include <math.h>

#define BATCH 2
#define SEQ   2048
#define NH    32
#define HID   2048
#define CHUNK 256
#define NCH   8
#define NBCH  (BATCH*NCH*NH)   // 512
#define PST   72               // padded bf16 LDS leading dim (b128-alignable)

typedef __attribute__((ext_vector_type(4))) float f32x4;
typedef __attribute__((ext_vector_type(8))) short bf16x8;
typedef unsigned int uint;
typedef unsigned short ushort;

__device__ __forceinline__ float softplusf(float x) {
    return x > 20.f ? x : log1pf(expf(x));
}

__device__ __forceinline__ short f2bf(float f) {
    union { float f; uint u; } v; v.f = f;
    uint r = v.u + 0x7FFF + ((v.u >> 16) & 1);
    return (short)(r >> 16);
}
__device__ __forceinline__ float bf2f(ushort s) {
    union { uint u; float f; } v; v.u = ((uint)s) << 16; return v.f;
}
__device__ __forceinline__ uint packbf2(float lo, float hi) {
    return (uint)(ushort)f2bf(lo) | ((uint)(ushort)f2bf(hi) << 16);
}

struct BF8 { union { bf16x8 v; short s[8]; }; };

__device__ __forceinline__ bf16x8 load_cvt8(const float* p, float scale) {
    float4 a = *(const float4*)p;
    float4 b = *(const float4*)(p + 4);
    BF8 r;
    r.s[0]=f2bf(a.x*scale); r.s[1]=f2bf(a.y*scale); r.s[2]=f2bf(a.z*scale); r.s[3]=f2bf(a.w*scale);
    r.s[4]=f2bf(b.x*scale); r.s[5]=f2bf(b.y*scale); r.s[6]=f2bf(b.z*scale); r.s[7]=f2bf(b.w*scale);
    return r.v;
}

#define MFMA(a,b,c) __builtin_amdgcn_mfma_f32_16x16x32_bf16((a),(b),(c),0,0,0)

// ---------------------------------------------------------------------------
// K1: dt/g projections (fp32 kept for dt precision; optimize next round)
// ---------------------------------------------------------------------------
__global__ __launch_bounds__(256) void k_proj(
    const float* __restrict__ hs_ab, const float* __restrict__ hs_g,
    const float* __restrict__ dt_w, const float* __restrict__ dt_b,
    const float* __restrict__ g_w,  const float* __restrict__ g_b,
    const float* __restrict__ dt_bias,
    float* __restrict__ dt_out, float* __restrict__ g_out)
{
    __shared__ float red[256];
    int r = blockIdx.x;
    int t = threadIdx.x;
    int h = t & 31;
    int which = (t >> 5) & 1;
    int slice = t >> 6;
    const float* hid = which ? hs_g : hs_ab;
    const float* w   = which ? g_w  : dt_w;
    const float* hrow = hid + (size_t)r * HID + slice * 512;
    const float* wp   = w + (size_t)(slice * 512) * NH + h;
    float sum = 0.f;
    #pragma unroll 4
    for (int k = 0; k < 512; ++k)
        sum += hrow[k] * wp[(size_t)k * NH];
    red[t] = sum;
    __syncthreads();
    if (t < 64) {
        float tot = red[t] + red[t + 64] + red[t + 128] + red[t + 192];
        int hh = t & 31;
        if ((t >> 5) == 0)
            dt_out[(size_t)r * NH + hh] = softplusf(tot + dt_b[hh] + dt_bias[hh]);
        else
            g_out[(size_t)r * NH + hh] = tot + g_b[hh];
    }
}

// ---------------------------------------------------------------------------
// K2: inverse L2 norms
// ---------------------------------------------------------------------------
__global__ __launch_bounds__(256) void k_norms(
    const float* __restrict__ q, const float* __restrict__ k,
    float* __restrict__ invC, float* __restrict__ invB)
{
    int t = threadIdx.x;
    int lane = t & 63;
    size_t row = (size_t)blockIdx.x * 4 + (t >> 6);
    float qv = q[row * 64 + lane];
    float kv = k[row * 64 + lane];
    float sq = qv * qv, sk = kv * kv;
    #pragma unroll
    for (int off = 32; off > 0; off >>= 1) {
        sq += __shfl_down(sq, off);
        sk += __shfl_down(sk, off);
    }
    if (lane == 0) {
        invC[row] = 1.f / fmaxf(sqrtf(sq), 1e-12f);
        invB[row] = 1.f / fmaxf(sqrtf(sk), 1e-12f);
    }
}

// ---------------------------------------------------------------------------
// K3: per (b,c,h) cumsum of dt*A; chunk-ordered cum/dt/w; chunk decay
// ---------------------------------------------------------------------------
__global__ __launch_bounds__(256) void k_cumsum(
    const float* __restrict__ dt, const float* __restrict__ A_log,
    float* __restrict__ cumc, float* __restrict__ wvc,
    float* __restrict__ dtc, float* __restrict__ cd)
{
    __shared__ float sC[256];
    int bch = blockIdx.x;
    int h = bch & 31, c = (bch >> 5) & 7, b = bch >> 8;
    int t = threadIdx.x;
    size_t row = ((size_t)b * SEQ + c * CHUNK + t) * NH + h;
    float dt_l = dt[row];
    float A = -expf(A_log[h]);
    sC[t] = dt_l * A;
    __syncthreads();
    for (int off = 1; off < 256; off <<= 1) {
        float v = (t >= off) ? sC[t - off] : 0.f;
        __syncthreads();
        sC[t] += v;
        __syncthreads();
    }
    float cum = sC[t], cl = sC[255];
    size_t o = (size_t)bch * CHUNK + t;
    cumc[o] = cum;
    wvc[o] = expf(cl - cum) * dt_l;
    dtc[o] = dt_l;
    if (t == 255) cd[bch] = expf(cl);
}

// ---------------------------------------------------------------------------
// K4: partial chunk states (unchanged)
// ---------------------------------------------------------------------------
__global__ __launch_bounds__(256) void k_states(
    const float* __restrict__ kst, const float* __restrict__ vst,
    const float* __restrict__ invB, const float* __restrict__ wvc,
    float* __restrict__ sp)
{
    __shared__ float kS[64 * 64];
    __shared__ float xS[64 * 64];
    int blk = blockIdx.x;
    int half = blk & 1, bch = blk >> 1;
    int h = bch & 31, c = (bch >> 5) & 7, b = bch >> 8;
    int t = threadIdx.x;
    size_t rowbase = (size_t)b * SEQ + c * CHUNK + half * 128;
    int pg = (t & 15) * 4, ng = (t >> 4) * 4;
    float acc[4][4];
    #pragma unroll
    for (int i = 0; i < 4; ++i)
        #pragma unroll
        for (int j = 0; j < 4; ++j) acc[i][j] = 0.f;

    for (int tt = 0; tt < 2; ++tt) {
        int r0 = t >> 4;
        int c4 = (t & 15) * 4;
        #pragma unroll
        for (int i = 0; i < 4; ++i) {
            int row = r0 + i * 16;
            size_t grow = (rowbase + tt * 64 + row) * NH + h;
            float w  = wvc[(size_t)bch * CHUNK + half * 128 + tt * 64 + row];
            float ib = invB[grow];
            float4 kv = *(const float4*)(kst + grow * 64 + c4);
            float4 xv = *(const float4*)(vst + grow * 64 + c4);
            *(float4*)(kS + row * 64 + c4) =
                make_float4(kv.x * ib, kv.y * ib, kv.z * ib, kv.w * ib);
            *(float4*)(xS + row * 64 + c4) =
                make_float4(xv.x * w, xv.y * w, xv.z * w, xv.w * w);
        }
        __syncthreads();
        for (int ll = 0; ll < 64; ++ll) {
            float4 x4 = *(const float4*)(xS + ll * 64 + pg);
            float4 k4 = *(const float4*)(kS + ll * 64 + ng);
            acc[0][0] += x4.x * k4.x; acc[0][1] += x4.x * k4.y;
            acc[0][2] += x4.x * k4.z; acc[0][3] += x4.x * k4.w;
            acc[1][0] += x4.y * k4.x; acc[1][1] += x4.y * k4.y;
            acc[1][2] += x4.y * k4.z; acc[1][3] += x4.y * k4.w;
            acc[2][0] += x4.z * k4.x; acc[2][1] += x4.z * k4.y;
            acc[2][2] += x4.z * k4.z; acc[2][3] += x4.z * k4.w;
            acc[3][0] += x4.w * k4.x; acc[3][1] += x4.w * k4.y;
            acc[3][2] += x4.w * k4.z; acc[3][3] += x4.w * k4.w;
        }
        __syncthreads();
    }
    size_t obase = (size_t)blk * 4096;
    #pragma unroll
    for (int i = 0; i < 4; ++i)
        *(float4*)(sp + obase + (pg + i) * 64 + ng) =
            make_float4(acc[i][0], acc[i][1], acc[i][2], acc[i][3]);
}

// ---------------------------------------------------------------------------
// K5: inter-chunk scan (unchanged)
// ---------------------------------------------------------------------------
__global__ __launch_bounds__(256) void k_scan(
    const float* __restrict__ sp, const float* __restrict__ cd,
    float* __restrict__ Hp)
{
    size_t id = (size_t)blockIdx.x * 256 + threadIdx.x;
    size_t bh = id >> 12, pn = id & 4095;
    size_t b = bh >> 5, h = bh & 31;
    float carry = 0.f;
    for (int c = 0; c < NCH; ++c) {
        size_t bch = (b * NCH + c) * NH + h;
        float st = sp[(bch * 2) * 4096 + pn] + sp[(bch * 2 + 1) * 4096 + pn];
        Hp[bch * 4096 + pn] = carry;
        carry = cd[bch] * carry + st;
    }
}

// ---------------------------------------------------------------------------
// K6: MFMA intra-chunk + H_prev. Block = one (b,c,h), 4 waves.
// Wave w owns l-strips {w, 7-w} (32 rows each, load-balanced).
// S' = B·C^T (D[m=s][n=l]) -> decay/mask -> P_lds[l][s] (wave-private)
// Y  = P·XdT^T + C·Hp^T, acc in C/D layout, scaled H-term first.
// ---------------------------------------------------------------------------
__global__ __launch_bounds__(256, 2) void k_intra(
    const float* __restrict__ qst, const float* __restrict__ kst,
    const float* __restrict__ vst,
    const float* __restrict__ invC, const float* __restrict__ invB,
    const float* __restrict__ cumc, const float* __restrict__ dtc,
    const float* __restrict__ Hp,
    short* __restrict__ ygb)
{
    __shared__ short B_s[64 * PST];     // B[s][n] bf16, invB-scaled
    __shared__ short XT_s[64 * PST];    // XdT[p][s] bf16, dt-scaled
    __shared__ short P_s[4 * 32 * PST]; // per-wave P[l][s] bf16
    __shared__ float sCum[256];
    __shared__ float sDt[256];

    int bch = blockIdx.x;
    int h = bch & 31, c = (bch >> 5) & 7, b = bch >> 8;
    int t = threadIdx.x;
    int w = t >> 6, lane = t & 63;
    int quad = lane >> 4, l16 = lane & 15;
    size_t rowbase = (size_t)b * SEQ + c * CHUNK;

    sCum[t] = cumc[(size_t)bch * CHUNK + t];
    sDt[t]  = dtc[(size_t)bch * CHUNK + t];
    __syncthreads();

    // C fragments (bf16, invC-scaled) direct from global: [is][lt][kn]
    bf16x8 cf[2][2][2];
    #pragma unroll
    for (int is = 0; is < 2; ++is) {
        int strip = is ? (7 - w) : w;
        #pragma unroll
        for (int lt = 0; lt < 2; ++lt) {
            int l = strip * 32 + lt * 16 + l16;
            size_t grow = (rowbase + l) * NH + h;
            float ic = invC[grow];
            const float* qp = qst + grow * 64 + quad * 8;
            cf[is][lt][0] = load_cvt8(qp, ic);
            cf[is][lt][1] = load_cvt8(qp + 32, ic);
        }
    }

    f32x4 acc[2][2][4];
    #pragma unroll
    for (int is = 0; is < 2; ++is)
        #pragma unroll
        for (int lt = 0; lt < 2; ++lt)
            #pragma unroll
            for (int pt = 0; pt < 4; ++pt)
                acc[is][lt][pt] = (f32x4){0.f, 0.f, 0.f, 0.f};

    // ---- H-term first: acc = C · Hp^T ----
    {
        bf16x8 hf[4][2];
        #pragma unroll
        for (int pt = 0; pt < 4; ++pt) {
            const float* hp = Hp + (size_t)bch * 4096 + (pt * 16 + l16) * 64 + quad * 8;
            hf[pt][0] = load_cvt8(hp, 1.f);
            hf[pt][1] = load_cvt8(hp + 32, 1.f);
        }
        #pragma unroll
        for (int is = 0; is < 2; ++is)
            #pragma unroll
            for (int lt = 0; lt < 2; ++lt)
                #pragma unroll
                for (int pt = 0; pt < 4; ++pt) {
                    acc[is][lt][pt] = MFMA(cf[is][lt][0], hf[pt][0], acc[is][lt][pt]);
                    acc[is][lt][pt] = MFMA(cf[is][lt][1], hf[pt][1], acc[is][lt][pt]);
                }
    }
    // scale H-term by exp(cum_l); l = strip*32 + lt*16 + quad*4 + r
    #pragma unroll
    for (int is = 0; is < 2; ++is) {
        int strip = is ? (7 - w) : w;
        #pragma unroll
        for (int lt = 0; lt < 2; ++lt) {
            float e[4];
            #pragma unroll
            for (int r = 0; r < 4; ++r)
                e[r] = __expf(sCum[strip * 32 + lt * 16 + quad * 4 + r]);
            #pragma unroll
            for (int pt = 0; pt < 4; ++pt)
                #pragma unroll
                for (int r = 0; r < 4; ++r)
                    acc[is][lt][pt][r] *= e[r];
        }
    }

    short* Pw = P_s + w * 32 * PST;

    for (int st = 0; st < 4; ++st) {
        __syncthreads();
        {   // stage B (4 lanes/row, b128 writes)
            int ss = t >> 2, q4 = (t & 3) * 16;
            size_t grow = (rowbase + st * 64 + ss) * NH + h;
            float ib = invB[grow];
            const float4* kp = (const float4*)(kst + grow * 64 + q4);
            float4 v0 = kp[0], v1 = kp[1], v2 = kp[2], v3 = kp[3];
            uint u[8];
            u[0] = packbf2(v0.x * ib, v0.y * ib); u[1] = packbf2(v0.z * ib, v0.w * ib);
            u[2] = packbf2(v1.x * ib, v1.y * ib); u[3] = packbf2(v1.z * ib, v1.w * ib);
            u[4] = packbf2(v2.x * ib, v2.y * ib); u[5] = packbf2(v2.z * ib, v2.w * ib);
            u[6] = packbf2(v3.x * ib, v3.y * ib); u[7] = packbf2(v3.z * ib, v3.w * ib);
            uint* dst = (uint*)(B_s + ss * PST + q4);
            *(uint4*)dst = make_uint4(u[0], u[1], u[2], u[3]);
            *(uint4*)(dst + 4) = make_uint4(u[4], u[5], u[6], u[7]);
        }
        {   // stage XdT (pair-packed b32 transpose writes: 2-way conflicts only)
            int ss2 = t & 31, qh = t >> 5;
            int p0 = qh * 8;
            size_t g0 = (rowbase + st * 64 + 2 * ss2) * NH + h;
            size_t g1 = g0 + NH;
            float dt0 = sDt[st * 64 + 2 * ss2];
            float dt1 = sDt[st * 64 + 2 * ss2 + 1];
            float4 a0 = *(const float4*)(vst + g0 * 64 + p0);
            float4 a1 = *(const float4*)(vst + g0 * 64 + p0 + 4);
            float4 b0 = *(const float4*)(vst + g1 * 64 + p0);
            float4 b1 = *(const float4*)(vst + g1 * 64 + p0 + 4);
            float x0[8] = {a0.x, a0.y, a0.z, a0.w, a1.x, a1.y, a1.z, a1.w};
            float x1[8] = {b0.x, b0.y, b0.z, b0.w, b1.x, b1.y, b1.z, b1.w};
            uint* xt = (uint*)XT_s;
            #pragma unroll
            for (int i = 0; i < 8; ++i)
                xt[(p0 + i) * (PST / 2) + ss2] = packbf2(x0[i] * dt0, x1[i] * dt1);
        }
        __syncthreads();

        // XdT b-frags for this tile
        bf16x8 xf[4][2];
        #pragma unroll
        for (int pt = 0; pt < 4; ++pt) {
            #pragma unroll
            for (int ks = 0; ks < 2; ++ks)
                xf[pt][ks] = *(const bf16x8*)(XT_s + (pt * 16 + l16) * PST + ks * 32 + quad * 8);
        }

        #pragma unroll
        for (int is = 0; is < 2; ++is) {
            int strip = is ? (7 - w) : w;
            int L0 = strip * 32;
            if (L0 + 31 < st * 64) continue;   // wave-uniform

            // S' = B·C^T -> decay/mask -> P_lds
            #pragma unroll
            for (int lt = 0; lt < 2; ++lt) {
                int Lt = L0 + lt * 16;
                float cl = sCum[Lt + l16];
                int lrow = lt * 16 + l16;
                #pragma unroll
                for (int mt = 0; mt < 4; ++mt) {
                    int S0 = st * 64 + mt * 16;
                    uint* pdst = (uint*)(Pw + lrow * PST + mt * 16 + quad * 4);
                    if (S0 > Lt + 15) {   // fully masked tile
                        *(uint2*)pdst = make_uint2(0u, 0u);
                        continue;
                    }
                    f32x4 sa = (f32x4){0.f, 0.f, 0.f, 0.f};
                    bf16x8 af0 = *(const bf16x8*)(B_s + (mt * 16 + l16) * PST + quad * 8);
                    bf16x8 af1 = *(const bf16x8*)(B_s + (mt * 16 + l16) * PST + 32 + quad * 8);
                    sa = MFMA(af0, cf[is][lt][0], sa);
                    sa = MFMA(af1, cf[is][lt][1], sa);
                    float vals[4];
                    #pragma unroll
                    for (int r = 0; r < 4; ++r) {
                        int s = S0 + quad * 4 + r;
                        float v = sa[r] * __expf(cl - sCum[s]);
                        vals[r] = (Lt + l16 >= s) ? v : 0.f;
                    }
                    *(uint2*)pdst = make_uint2(packbf2(vals[0], vals[1]),
                                               packbf2(vals[2], vals[3]));
                }
            }
            // PV: acc += P · XdT^T
            #pragma unroll
            for (int lt = 0; lt < 2; ++lt) {
                int Lmax = L0 + lt * 16 + 15;
                #pragma unroll
                for (int ks = 0; ks < 2; ++ks) {
                    if (st * 64 + ks * 32 > Lmax) continue;
                    bf16x8 af = *(const bf16x8*)(Pw + (lt * 16 + l16) * PST + ks * 32 + quad * 8);
                    #pragma unroll
                    for (int pt = 0; pt < 4; ++pt)
                        acc[is][lt][pt] = MFMA(af, xf[pt][ks], acc[is][lt][pt]);
                }
            }
        }
    }

    // epilogue: store y as bf16
    #pragma unroll
    for (int is = 0; is < 2; ++is) {
        int strip = is ? (7 - w) : w;
        #pragma unroll
        for (int lt = 0; lt < 2; ++lt)
            #pragma unroll
            for (int pt = 0; pt < 4; ++pt)
                #pragma unroll
                for (int r = 0; r < 4; ++r) {
                    int l = strip * 32 + lt * 16 + quad * 4 + r;
                    int p = pt * 16 + l16;
                    ygb[((rowbase + l) * NH + h) * 64 + p] = f2bf(acc[is][lt][pt][r]);
                }
    }
}

// ---------------------------------------------------------------------------
// K7: gate + RMSNorm: ygn = (y*silu(g)) * rsqrt(mean+eps) * norm_w  (bf16)
// ---------------------------------------------------------------------------
__global__ __launch_bounds__(256) void k_gate(
    const short* __restrict__ ygb, const float* __restrict__ g_ws,
    const float* __restrict__ norm_w, short* __restrict__ ygn)
{
    __shared__ float sil[32];
    __shared__ float red[256];
    int r = blockIdx.x;
    int t = threadIdx.x;
    if (t < 32) {
        float g = g_ws[(size_t)r * 32 + t];
        sil[t] = g / (1.f + expf(-g));
    }
    __syncthreads();
    uint4 u = *(const uint4*)(ygb + (size_t)r * 2048 + t * 8);
    float s = sil[t >> 3];
    float v[8];
    v[0] = bf2f(u.x & 0xFFFF) * s; v[1] = bf2f(u.x >> 16) * s;
    v[2] = bf2f(u.y & 0xFFFF) * s; v[3] = bf2f(u.y >> 16) * s;
    v[4] = bf2f(u.z & 0xFFFF) * s; v[5] = bf2f(u.z >> 16) * s;
    v[6] = bf2f(u.w & 0xFFFF) * s; v[7] = bf2f(u.w >> 16) * s;
    float ssq = 0.f;
    #pragma unroll
    for (int i = 0; i < 8; ++i) ssq += v[i] * v[i];
    red[t] = ssq;
    __syncthreads();
    for (int off = 128; off > 0; off >>= 1) {
        if (t < off) red[t] += red[t + off];
        __syncthreads();
    }
    float scale = rsqrtf(red[0] / 2048.f + 1e-5f);
    const float* nw = norm_w + t * 8;
    uint4 o;
    o.x = packbf2(v[0] * scale * nw[0], v[1] * scale * nw[1]);
    o.y = packbf2(v[2] * scale * nw[2], v[3] * scale * nw[3]);
    o.z = packbf2(v[4] * scale * nw[4], v[5] * scale * nw[5]);
    o.w = packbf2(v[6] * scale * nw[6], v[7] * scale * nw[7]);
    *(uint4*)(ygn + (size_t)r * 2048 + t * 8) = o;
}

// ---------------------------------------------------------------------------
// K8: per-head o_proj via MFMA. Block = (h, 256-row tile), 4 waves x 64 rows.
// out[row][h*64+q] = sum_p ygn[row][h*64+p] * o_w[h][p][q] + o_b[h][q]
// ---------------------------------------------------------------------------
__global__ __launch_bounds__(256) void k_oproj(
    const short* __restrict__ ygn, const float* __restrict__ o_w,
    const float* __restrict__ o_b, float* __restrict__ out)
{
    __shared__ short wT[64 * PST];   // [q][p] bf16
    int blk = blockIdx.x;
    int h = blk & 31, rt = blk >> 5;
    int t = threadIdx.x;
    int w = t >> 6, lane = t & 63;
    int quad = lane >> 4, l16 = lane & 15;

    {   // stage o_w[h] transposed
        int p = t >> 2, q4 = (t & 3) * 16;
        const float* wp = o_w + (size_t)h * 4096 + p * 64 + q4;
        float4 v0 = *(const float4*)wp, v1 = *(const float4*)(wp + 4);
        float4 v2 = *(const float4*)(wp + 8), v3 = *(const float4*)(wp + 12);
        float vv[16] = {v0.x,v0.y,v0.z,v0.w, v1.x,v1.y,v1.z,v1.w,
                        v2.x,v2.y,v2.z,v2.w, v3.x,v3.y,v3.z,v3.w};
        #pragma unroll
        for (int i = 0; i < 16; ++i)
            wT[(q4 + i) * PST + p] = f2bf(vv[i]);
    }
    __syncthreads();

    bf16x8 bfr[4][2];
    #pragma unroll
    for (int nt = 0; nt < 4; ++nt)
        #pragma unroll
        for (int ks = 0; ks < 2; ++ks)
            bfr[nt][ks] = *(const bf16x8*)(wT + (nt * 16 + l16) * PST + ks * 32 + quad * 8);

    int rowbase = rt * 256 + w * 64;
    f32x4 acc[4][4];
    #pragma unroll
    for (int nt = 0; nt < 4; ++nt) {
        float bv = o_b[h * 64 + nt * 16 + l16];
        #pragma unroll
        for (int mt = 0; mt < 4; ++mt)
            acc[mt][nt] = (f32x4){bv, bv, bv, bv};
    }
    #pragma unroll
    for (int ks = 0; ks < 2; ++ks) {
        #pragma unroll
        for (int mt = 0; mt < 4; ++mt) {
            int row = rowbase + mt * 16 + l16;
            bf16x8 af = *(const bf16x8*)(ygn + (size_t)row * 2048 + h * 64 + ks * 32 + quad * 8);
            #pragma unroll
            for (int nt = 0; nt < 4; ++nt)
                acc[mt][nt] = MFMA(af, bfr[nt][ks], acc[mt][nt]);
        }
    }
    #pragma unroll
    for (int mt = 0; mt < 4; ++mt)
        #pragma unroll
        for (int nt = 0; nt < 4; ++nt)
            #pragma unroll
            for (int r = 0; r < 4; ++r) {
                int row = rowbase + mt * 16 + quad * 4 + r;
                out[(size_t)row * 2048 + h * 64 + nt * 16 + l16] = acc[mt][nt][r];
            }
}

extern "C" void kernel_launch(void* const* d_in, const int* in_sizes, int n_in,
                              void* d_out, int out_size, void* d_ws, size_t ws_size,
                              hipStream_t stream) {
    const float* hs_ab   = (const float*)d_in[0];
    const float* hs_g    = (const float*)d_in[1];
    const float* qst     = (const float*)d_in[2];
    const float* kst     = (const float*)d_in[3];
    const float* vst     = (const float*)d_in[4];
    const float* dt_w    = (const float*)d_in[5];
    const float* dt_b    = (const float*)d_in[6];
    const float* g_w     = (const float*)d_in[7];
    const float* g_b     = (const float*)d_in[8];
    const float* A_log   = (const float*)d_in[9];
    const float* dt_bias = (const float*)d_in[10];
    const float* norm_w  = (const float*)d_in[11];
    const float* o_w     = (const float*)d_in[12];
    const float* o_b     = (const float*)d_in[13];
    float* out = (float*)d_out;

    float* ws = (float*)d_ws;
    size_t off = 0;
    float* dt_ws  = ws + off; off += (size_t)BATCH * SEQ * NH;
    float* g_ws   = ws + off; off += (size_t)BATCH * SEQ * NH;
    float* invC   = ws + off; off += (size_t)BATCH * SEQ * NH;
    float* invB   = ws + off; off += (size_t)BATCH * SEQ * NH;
    float* cumc   = ws + off; off += (size_t)NBCH * CHUNK;
    float* wvc    = ws + off; off += (size_t)NBCH * CHUNK;
    float* dtc    = ws + off; off += (size_t)NBCH * CHUNK;
    float* cd_ws  = ws + off; off += (size_t)NBCH;
    float* sp     = ws + off; off += (size_t)NBCH * 2 * 4096;    // 67 MB
    float* Hp     = ws + off; off += (size_t)NBCH * 4096;        // 8.4 MB

    // bf16 y buffers aliased onto sp (dead after k_scan)
    short* ygb = (short*)sp;
    short* ygn = (short*)sp + (size_t)BATCH * SEQ * NH * 64;

    k_proj<<<BATCH * SEQ, 256, 0, stream>>>(hs_ab, hs_g, dt_w, dt_b, g_w, g_b,
                                            dt_bias, dt_ws, g_ws);
    k_norms<<<BATCH * SEQ * NH / 4, 256, 0, stream>>>(qst, kst, invC, invB);
    k_cumsum<<<NBCH, 256, 0, stream>>>(dt_ws, A_log, cumc, wvc, dtc, cd_ws);
    k_states<<<NBCH * 2, 256, 0, stream>>>(kst, vst, invB, wvc, sp);
    k_scan<<<BATCH * NH * 4096 / 256, 256, 0, stream>>>(sp, cd_ws, Hp);
    k_intra<<<NBCH, 256, 0, stream>>>(qst, kst, vst, invC, invB,
                                      cumc, dtc, Hp, ygb);
    k_gate<<<BATCH * SEQ, 256, 0, stream>>>(ygb, g_ws, norm_w, ygn);
    k_oproj<<<32 * (BATCH * SEQ / 256), 256, 0, stream>>>(ygn, o_w, o_b, out);
}

// Round 4
// 291.008 us; speedup vs baseline: 2.6202x; 1.3984x over previous
//
#include <hip/hip_runtime.h>
#include <math.h>

#define BATCH 2
#define SEQ   2048
#define NH    32
#define HID   2048
#define CHUNK 256
#define NCH   8
#define NBCH  (BATCH*NCH*NH)   // 512
#define PST   72               // padded bf16 LDS leading dim (b128-alignable)
#define BK    256
#define APST  264              // BK+8 shorts; row stride 528 B = 33*16 (b128-aligned)

typedef __attribute__((ext_vector_type(4))) float f32x4;
typedef __attribute__((ext_vector_type(8))) short bf16x8;
typedef unsigned int uint;
typedef unsigned short ushort;

__device__ __forceinline__ float softplusf(float x) {
    return x > 20.f ? x : log1pf(expf(x));
}

__device__ __forceinline__ short f2bf(float f) {
    union { float f; uint u; } v; v.f = f;
    uint r = v.u + 0x7FFF + ((v.u >> 16) & 1);
    return (short)(r >> 16);
}
__device__ __forceinline__ float bf2f(ushort s) {
    union { uint u; float f; } v; v.u = ((uint)s) << 16; return v.f;
}
__device__ __forceinline__ uint packbf2(float lo, float hi) {
    return (uint)(ushort)f2bf(lo) | ((uint)(ushort)f2bf(hi) << 16);
}

struct BF8 { union { bf16x8 v; short s[8]; }; };

__device__ __forceinline__ bf16x8 load_cvt8(const float* p, float scale) {
    float4 a = *(const float4*)p;
    float4 b = *(const float4*)(p + 4);
    BF8 r;
    r.s[0]=f2bf(a.x*scale); r.s[1]=f2bf(a.y*scale); r.s[2]=f2bf(a.z*scale); r.s[3]=f2bf(a.w*scale);
    r.s[4]=f2bf(b.x*scale); r.s[5]=f2bf(b.y*scale); r.s[6]=f2bf(b.z*scale); r.s[7]=f2bf(b.w*scale);
    return r.v;
}

#define MFMA(a,b,c) __builtin_amdgcn_mfma_f32_16x16x32_bf16((a),(b),(c),0,0,0)

// ---------------------------------------------------------------------------
// K1: dt/g projections as bf16 MFMA GEMM.
// Block = (which, 32-row tile); grid 256. 4 waves = (m-half, n-half) quadrants.
// K-loop BK=256: A-tile 32x256 bf16 + W^T-tile 32x256 bf16 in LDS.
// ---------------------------------------------------------------------------
__global__ __launch_bounds__(256) void k_proj(
    const float* __restrict__ hs_ab, const float* __restrict__ hs_g,
    const float* __restrict__ dt_w, const float* __restrict__ dt_b,
    const float* __restrict__ g_w,  const float* __restrict__ g_b,
    const float* __restrict__ dt_bias,
    float* __restrict__ dt_out, float* __restrict__ g_out)
{
    __shared__ short As[32 * APST];
    __shared__ short Bs[32 * APST];
    int which = blockIdx.x & 1;
    int rt = blockIdx.x >> 1;
    int r0 = rt * 32;
    const float* Am = which ? hs_g : hs_ab;
    const float* W  = which ? g_w  : dt_w;
    int t = threadIdx.x;
    int w = t >> 6, lane = t & 63, quad = lane >> 4, l16 = lane & 15;
    int mh = w & 1, nh = w >> 1;

    f32x4 acc = (f32x4){0.f, 0.f, 0.f, 0.f};

    for (int kc = 0; kc < HID; kc += BK) {
        __syncthreads();
        {   // stage A: 32 rows x BK cols, bf16-packed
            int row = t >> 3, k0 = (t & 7) * 32;
            const float* src = Am + (size_t)(r0 + row) * HID + kc + k0;
            uint* dst = (uint*)(As + row * APST + k0);
            #pragma unroll
            for (int i = 0; i < 4; ++i) {
                float4 a = *(const float4*)(src + i * 8);
                float4 b = *(const float4*)(src + i * 8 + 4);
                dst[i*4+0] = packbf2(a.x, a.y); dst[i*4+1] = packbf2(a.z, a.w);
                dst[i*4+2] = packbf2(b.x, b.y); dst[i*4+3] = packbf2(b.z, b.w);
            }
        }
        if (t < 128) {   // stage W transposed: Bs[n][k] = W[kc+k][n], pair-packed
            int k2 = t * 2;
            const float* w0 = W + (size_t)(kc + k2) * NH;
            const float* w1 = w0 + NH;
            #pragma unroll
            for (int n = 0; n < 32; n += 4) {
                float4 a = *(const float4*)(w0 + n);
                float4 b = *(const float4*)(w1 + n);
                *((uint*)(Bs + (n+0) * APST + k2)) = packbf2(a.x, b.x);
                *((uint*)(Bs + (n+1) * APST + k2)) = packbf2(a.y, b.y);
                *((uint*)(Bs + (n+2) * APST + k2)) = packbf2(a.z, b.z);
                *((uint*)(Bs + (n+3) * APST + k2)) = packbf2(a.w, b.w);
            }
        }
        __syncthreads();
        #pragma unroll
        for (int ks = 0; ks < BK / 32; ++ks) {
            bf16x8 af = *(const bf16x8*)(As + (mh*16 + l16) * APST + ks*32 + quad*8);
            bf16x8 bf = *(const bf16x8*)(Bs + (nh*16 + l16) * APST + ks*32 + quad*8);
            acc = MFMA(af, bf, acc);
        }
    }

    int n = nh * 16 + l16;
    int Rb = r0 + mh * 16 + quad * 4;
    if (which == 0) {
        float bb = dt_b[n] + dt_bias[n];
        #pragma unroll
        for (int r = 0; r < 4; ++r)
            dt_out[(size_t)(Rb + r) * NH + n] = softplusf(acc[r] + bb);
    } else {
        float bb = g_b[n];
        #pragma unroll
        for (int r = 0; r < 4; ++r)
            g_out[(size_t)(Rb + r) * NH + n] = acc[r] + bb;
    }
}

// ---------------------------------------------------------------------------
// K2: inverse L2 norms
// ---------------------------------------------------------------------------
__global__ __launch_bounds__(256) void k_norms(
    const float* __restrict__ q, const float* __restrict__ k,
    float* __restrict__ invC, float* __restrict__ invB)
{
    int t = threadIdx.x;
    int lane = t & 63;
    size_t row = (size_t)blockIdx.x * 4 + (t >> 6);
    float qv = q[row * 64 + lane];
    float kv = k[row * 64 + lane];
    float sq = qv * qv, sk = kv * kv;
    #pragma unroll
    for (int off = 32; off > 0; off >>= 1) {
        sq += __shfl_down(sq, off);
        sk += __shfl_down(sk, off);
    }
    if (lane == 0) {
        invC[row] = 1.f / fmaxf(sqrtf(sq), 1e-12f);
        invB[row] = 1.f / fmaxf(sqrtf(sk), 1e-12f);
    }
}

// ---------------------------------------------------------------------------
// K3: per (b,c,h) cumsum of dt*A; chunk-ordered cum/dt/w; chunk decay
// ---------------------------------------------------------------------------
__global__ __launch_bounds__(256) void k_cumsum(
    const float* __restrict__ dt, const float* __restrict__ A_log,
    float* __restrict__ cumc, float* __restrict__ wvc,
    float* __restrict__ dtc, float* __restrict__ cd)
{
    __shared__ float sC[256];
    int bch = blockIdx.x;
    int h = bch & 31, c = (bch >> 5) & 7, b = bch >> 8;
    int t = threadIdx.x;
    size_t row = ((size_t)b * SEQ + c * CHUNK + t) * NH + h;
    float dt_l = dt[row];
    float A = -expf(A_log[h]);
    sC[t] = dt_l * A;
    __syncthreads();
    for (int off = 1; off < 256; off <<= 1) {
        float v = (t >= off) ? sC[t - off] : 0.f;
        __syncthreads();
        sC[t] += v;
        __syncthreads();
    }
    float cum = sC[t], cl = sC[255];
    size_t o = (size_t)bch * CHUNK + t;
    cumc[o] = cum;
    wvc[o] = expf(cl - cum) * dt_l;
    dtc[o] = dt_l;
    if (t == 255) cd[bch] = expf(cl);
}

// ---------------------------------------------------------------------------
// K4: partial chunk states
// ---------------------------------------------------------------------------
__global__ __launch_bounds__(256) void k_states(
    const float* __restrict__ kst, const float* __restrict__ vst,
    const float* __restrict__ invB, const float* __restrict__ wvc,
    float* __restrict__ sp)
{
    __shared__ float kS[64 * 64];
    __shared__ float xS[64 * 64];
    int blk = blockIdx.x;
    int half = blk & 1, bch = blk >> 1;
    int h = bch & 31, c = (bch >> 5) & 7, b = bch >> 8;
    int t = threadIdx.x;
    size_t rowbase = (size_t)b * SEQ + c * CHUNK + half * 128;
    int pg = (t & 15) * 4, ng = (t >> 4) * 4;
    float acc[4][4];
    #pragma unroll
    for (int i = 0; i < 4; ++i)
        #pragma unroll
        for (int j = 0; j < 4; ++j) acc[i][j] = 0.f;

    for (int tt = 0; tt < 2; ++tt) {
        int r0 = t >> 4;
        int c4 = (t & 15) * 4;
        #pragma unroll
        for (int i = 0; i < 4; ++i) {
            int row = r0 + i * 16;
            size_t grow = (rowbase + tt * 64 + row) * NH + h;
            float w  = wvc[(size_t)bch * CHUNK + half * 128 + tt * 64 + row];
            float ib = invB[grow];
            float4 kv = *(const float4*)(kst + grow * 64 + c4);
            float4 xv = *(const float4*)(vst + grow * 64 + c4);
            *(float4*)(kS + row * 64 + c4) =
                make_float4(kv.x * ib, kv.y * ib, kv.z * ib, kv.w * ib);
            *(float4*)(xS + row * 64 + c4) =
                make_float4(xv.x * w, xv.y * w, xv.z * w, xv.w * w);
        }
        __syncthreads();
        for (int ll = 0; ll < 64; ++ll) {
            float4 x4 = *(const float4*)(xS + ll * 64 + pg);
            float4 k4 = *(const float4*)(kS + ll * 64 + ng);
            acc[0][0] += x4.x * k4.x; acc[0][1] += x4.x * k4.y;
            acc[0][2] += x4.x * k4.z; acc[0][3] += x4.x * k4.w;
            acc[1][0] += x4.y * k4.x; acc[1][1] += x4.y * k4.y;
            acc[1][2] += x4.y * k4.z; acc[1][3] += x4.y * k4.w;
            acc[2][0] += x4.z * k4.x; acc[2][1] += x4.z * k4.y;
            acc[2][2] += x4.z * k4.z; acc[2][3] += x4.z * k4.w;
            acc[3][0] += x4.w * k4.x; acc[3][1] += x4.w * k4.y;
            acc[3][2] += x4.w * k4.z; acc[3][3] += x4.w * k4.w;
        }
        __syncthreads();
    }
    size_t obase = (size_t)blk * 4096;
    #pragma unroll
    for (int i = 0; i < 4; ++i)
        *(float4*)(sp + obase + (pg + i) * 64 + ng) =
            make_float4(acc[i][0], acc[i][1], acc[i][2], acc[i][3]);
}

// ---------------------------------------------------------------------------
// K5: inter-chunk scan
// ---------------------------------------------------------------------------
__global__ __launch_bounds__(256) void k_scan(
    const float* __restrict__ sp, const float* __restrict__ cd,
    float* __restrict__ Hp)
{
    size_t id = (size_t)blockIdx.x * 256 + threadIdx.x;
    size_t bh = id >> 12, pn = id & 4095;
    size_t b = bh >> 5, h = bh & 31;
    float carry = 0.f;
    for (int c = 0; c < NCH; ++c) {
        size_t bch = (b * NCH + c) * NH + h;
        float st = sp[(bch * 2) * 4096 + pn] + sp[(bch * 2 + 1) * 4096 + pn];
        Hp[bch * 4096 + pn] = carry;
        carry = cd[bch] * carry + st;
    }
}

// ---------------------------------------------------------------------------
// K6: MFMA intra-chunk + H_prev (unchanged from R3)
// ---------------------------------------------------------------------------
__global__ __launch_bounds__(256, 2) void k_intra(
    const float* __restrict__ qst, const float* __restrict__ kst,
    const float* __restrict__ vst,
    const float* __restrict__ invC, const float* __restrict__ invB,
    const float* __restrict__ cumc, const float* __restrict__ dtc,
    const float* __restrict__ Hp,
    short* __restrict__ ygb)
{
    __shared__ short B_s[64 * PST];
    __shared__ short XT_s[64 * PST];
    __shared__ short P_s[4 * 32 * PST];
    __shared__ float sCum[256];
    __shared__ float sDt[256];

    int bch = blockIdx.x;
    int h = bch & 31, c = (bch >> 5) & 7, b = bch >> 8;
    int t = threadIdx.x;
    int w = t >> 6, lane = t & 63;
    int quad = lane >> 4, l16 = lane & 15;
    size_t rowbase = (size_t)b * SEQ + c * CHUNK;

    sCum[t] = cumc[(size_t)bch * CHUNK + t];
    sDt[t]  = dtc[(size_t)bch * CHUNK + t];
    __syncthreads();

    bf16x8 cf[2][2][2];
    #pragma unroll
    for (int is = 0; is < 2; ++is) {
        int strip = is ? (7 - w) : w;
        #pragma unroll
        for (int lt = 0; lt < 2; ++lt) {
            int l = strip * 32 + lt * 16 + l16;
            size_t grow = (rowbase + l) * NH + h;
            float ic = invC[grow];
            const float* qp = qst + grow * 64 + quad * 8;
            cf[is][lt][0] = load_cvt8(qp, ic);
            cf[is][lt][1] = load_cvt8(qp + 32, ic);
        }
    }

    f32x4 acc[2][2][4];
    #pragma unroll
    for (int is = 0; is < 2; ++is)
        #pragma unroll
        for (int lt = 0; lt < 2; ++lt)
            #pragma unroll
            for (int pt = 0; pt < 4; ++pt)
                acc[is][lt][pt] = (f32x4){0.f, 0.f, 0.f, 0.f};

    {
        bf16x8 hf[4][2];
        #pragma unroll
        for (int pt = 0; pt < 4; ++pt) {
            const float* hp = Hp + (size_t)bch * 4096 + (pt * 16 + l16) * 64 + quad * 8;
            hf[pt][0] = load_cvt8(hp, 1.f);
            hf[pt][1] = load_cvt8(hp + 32, 1.f);
        }
        #pragma unroll
        for (int is = 0; is < 2; ++is)
            #pragma unroll
            for (int lt = 0; lt < 2; ++lt)
                #pragma unroll
                for (int pt = 0; pt < 4; ++pt) {
                    acc[is][lt][pt] = MFMA(cf[is][lt][0], hf[pt][0], acc[is][lt][pt]);
                    acc[is][lt][pt] = MFMA(cf[is][lt][1], hf[pt][1], acc[is][lt][pt]);
                }
    }
    #pragma unroll
    for (int is = 0; is < 2; ++is) {
        int strip = is ? (7 - w) : w;
        #pragma unroll
        for (int lt = 0; lt < 2; ++lt) {
            float e[4];
            #pragma unroll
            for (int r = 0; r < 4; ++r)
                e[r] = __expf(sCum[strip * 32 + lt * 16 + quad * 4 + r]);
            #pragma unroll
            for (int pt = 0; pt < 4; ++pt)
                #pragma unroll
                for (int r = 0; r < 4; ++r)
                    acc[is][lt][pt][r] *= e[r];
        }
    }

    short* Pw = P_s + w * 32 * PST;

    for (int st = 0; st < 4; ++st) {
        __syncthreads();
        {
            int ss = t >> 2, q4 = (t & 3) * 16;
            size_t grow = (rowbase + st * 64 + ss) * NH + h;
            float ib = invB[grow];
            const float4* kp = (const float4*)(kst + grow * 64 + q4);
            float4 v0 = kp[0], v1 = kp[1], v2 = kp[2], v3 = kp[3];
            uint u[8];
            u[0] = packbf2(v0.x * ib, v0.y * ib); u[1] = packbf2(v0.z * ib, v0.w * ib);
            u[2] = packbf2(v1.x * ib, v1.y * ib); u[3] = packbf2(v1.z * ib, v1.w * ib);
            u[4] = packbf2(v2.x * ib, v2.y * ib); u[5] = packbf2(v2.z * ib, v2.w * ib);
            u[6] = packbf2(v3.x * ib, v3.y * ib); u[7] = packbf2(v3.z * ib, v3.w * ib);
            uint* dst = (uint*)(B_s + ss * PST + q4);
            *(uint4*)dst = make_uint4(u[0], u[1], u[2], u[3]);
            *(uint4*)(dst + 4) = make_uint4(u[4], u[5], u[6], u[7]);
        }
        {
            int ss2 = t & 31, qh = t >> 5;
            int p0 = qh * 8;
            size_t g0 = (rowbase + st * 64 + 2 * ss2) * NH + h;
            size_t g1 = g0 + NH;
            float dt0 = sDt[st * 64 + 2 * ss2];
            float dt1 = sDt[st * 64 + 2 * ss2 + 1];
            float4 a0 = *(const float4*)(vst + g0 * 64 + p0);
            float4 a1 = *(const float4*)(vst + g0 * 64 + p0 + 4);
            float4 b0 = *(const float4*)(vst + g1 * 64 + p0);
            float4 b1 = *(const float4*)(vst + g1 * 64 + p0 + 4);
            float x0[8] = {a0.x, a0.y, a0.z, a0.w, a1.x, a1.y, a1.z, a1.w};
            float x1[8] = {b0.x, b0.y, b0.z, b0.w, b1.x, b1.y, b1.z, b1.w};
            uint* xt = (uint*)XT_s;
            #pragma unroll
            for (int i = 0; i < 8; ++i)
                xt[(p0 + i) * (PST / 2) + ss2] = packbf2(x0[i] * dt0, x1[i] * dt1);
        }
        __syncthreads();

        bf16x8 xf[4][2];
        #pragma unroll
        for (int pt = 0; pt < 4; ++pt) {
            #pragma unroll
            for (int ks = 0; ks < 2; ++ks)
                xf[pt][ks] = *(const bf16x8*)(XT_s + (pt * 16 + l16) * PST + ks * 32 + quad * 8);
        }

        #pragma unroll
        for (int is = 0; is < 2; ++is) {
            int strip = is ? (7 - w) : w;
            int L0 = strip * 32;
            if (L0 + 31 < st * 64) continue;

            #pragma unroll
            for (int lt = 0; lt < 2; ++lt) {
                int Lt = L0 + lt * 16;
                float cl = sCum[Lt + l16];
                int lrow = lt * 16 + l16;
                #pragma unroll
                for (int mt = 0; mt < 4; ++mt) {
                    int S0 = st * 64 + mt * 16;
                    uint* pdst = (uint*)(Pw + lrow * PST + mt * 16 + quad * 4);
                    if (S0 > Lt + 15) {
                        *(uint2*)pdst = make_uint2(0u, 0u);
                        continue;
                    }
                    f32x4 sa = (f32x4){0.f, 0.f, 0.f, 0.f};
                    bf16x8 af0 = *(const bf16x8*)(B_s + (mt * 16 + l16) * PST + quad * 8);
                    bf16x8 af1 = *(const bf16x8*)(B_s + (mt * 16 + l16) * PST + 32 + quad * 8);
                    sa = MFMA(af0, cf[is][lt][0], sa);
                    sa = MFMA(af1, cf[is][lt][1], sa);
                    float vals[4];
                    #pragma unroll
                    for (int r = 0; r < 4; ++r) {
                        int s = S0 + quad * 4 + r;
                        float v = sa[r] * __expf(cl - sCum[s]);
                        vals[r] = (Lt + l16 >= s) ? v : 0.f;
                    }
                    *(uint2*)pdst = make_uint2(packbf2(vals[0], vals[1]),
                                               packbf2(vals[2], vals[3]));
                }
            }
            #pragma unroll
            for (int lt = 0; lt < 2; ++lt) {
                int Lmax = L0 + lt * 16 + 15;
                #pragma unroll
                for (int ks = 0; ks < 2; ++ks) {
                    if (st * 64 + ks * 32 > Lmax) continue;
                    bf16x8 af = *(const bf16x8*)(Pw + (lt * 16 + l16) * PST + ks * 32 + quad * 8);
                    #pragma unroll
                    for (int pt = 0; pt < 4; ++pt)
                        acc[is][lt][pt] = MFMA(af, xf[pt][ks], acc[is][lt][pt]);
                }
            }
        }
    }

    #pragma unroll
    for (int is = 0; is < 2; ++is) {
        int strip = is ? (7 - w) : w;
        #pragma unroll
        for (int lt = 0; lt < 2; ++lt)
            #pragma unroll
            for (int pt = 0; pt < 4; ++pt)
                #pragma unroll
                for (int r = 0; r < 4; ++r) {
                    int l = strip * 32 + lt * 16 + quad * 4 + r;
                    int p = pt * 16 + l16;
                    ygb[((rowbase + l) * NH + h) * 64 + p] = f2bf(acc[is][lt][pt][r]);
                }
    }
}

// ---------------------------------------------------------------------------
// K7: gate + RMSNorm (bf16 in/out)
// ---------------------------------------------------------------------------
__global__ __launch_bounds__(256) void k_gate(
    const short* __restrict__ ygb, const float* __restrict__ g_ws,
    const float* __restrict__ norm_w, short* __restrict__ ygn)
{
    __shared__ float sil[32];
    __shared__ float red[256];
    int r = blockIdx.x;
    int t = threadIdx.x;
    if (t < 32) {
        float g = g_ws[(size_t)r * 32 + t];
        sil[t] = g / (1.f + expf(-g));
    }
    __syncthreads();
    uint4 u = *(const uint4*)(ygb + (size_t)r * 2048 + t * 8);
    float s = sil[t >> 3];
    float v[8];
    v[0] = bf2f(u.x & 0xFFFF) * s; v[1] = bf2f(u.x >> 16) * s;
    v[2] = bf2f(u.y & 0xFFFF) * s; v[3] = bf2f(u.y >> 16) * s;
    v[4] = bf2f(u.z & 0xFFFF) * s; v[5] = bf2f(u.z >> 16) * s;
    v[6] = bf2f(u.w & 0xFFFF) * s; v[7] = bf2f(u.w >> 16) * s;
    float ssq = 0.f;
    #pragma unroll
    for (int i = 0; i < 8; ++i) ssq += v[i] * v[i];
    red[t] = ssq;
    __syncthreads();
    for (int off = 128; off > 0; off >>= 1) {
        if (t < off) red[t] += red[t + off];
        __syncthreads();
    }
    float scale = rsqrtf(red[0] / 2048.f + 1e-5f);
    const float* nw = norm_w + t * 8;
    uint4 o;
    o.x = packbf2(v[0] * scale * nw[0], v[1] * scale * nw[1]);
    o.y = packbf2(v[2] * scale * nw[2], v[3] * scale * nw[3]);
    o.z = packbf2(v[4] * scale * nw[4], v[5] * scale * nw[5]);
    o.w = packbf2(v[6] * scale * nw[6], v[7] * scale * nw[7]);
    *(uint4*)(ygn + (size_t)r * 2048 + t * 8) = o;
}

// ---------------------------------------------------------------------------
// K8: per-head o_proj via MFMA
// ---------------------------------------------------------------------------
__global__ __launch_bounds__(256) void k_oproj(
    const short* __restrict__ ygn, const float* __restrict__ o_w,
    const float* __restrict__ o_b, float* __restrict__ out)
{
    __shared__ short wT[64 * PST];
    int blk = blockIdx.x;
    int h = blk & 31, rt = blk >> 5;
    int t = threadIdx.x;
    int w = t >> 6, lane = t & 63;
    int quad = lane >> 4, l16 = lane & 15;

    {
        int p = t >> 2, q4 = (t & 3) * 16;
        const float* wp = o_w + (size_t)h * 4096 + p * 64 + q4;
        float4 v0 = *(const float4*)wp, v1 = *(const float4*)(wp + 4);
        float4 v2 = *(const float4*)(wp + 8), v3 = *(const float4*)(wp + 12);
        float vv[16] = {v0.x,v0.y,v0.z,v0.w, v1.x,v1.y,v1.z,v1.w,
                        v2.x,v2.y,v2.z,v2.w, v3.x,v3.y,v3.z,v3.w};
        #pragma unroll
        for (int i = 0; i < 16; ++i)
            wT[(q4 + i) * PST + p] = f2bf(vv[i]);
    }
    __syncthreads();

    bf16x8 bfr[4][2];
    #pragma unroll
    for (int nt = 0; nt < 4; ++nt)
        #pragma unroll
        for (int ks = 0; ks < 2; ++ks)
            bfr[nt][ks] = *(const bf16x8*)(wT + (nt * 16 + l16) * PST + ks * 32 + quad * 8);

    int rowbase = rt * 256 + w * 64;
    f32x4 acc[4][4];
    #pragma unroll
    for (int nt = 0; nt < 4; ++nt) {
        float bv = o_b[h * 64 + nt * 16 + l16];
        #pragma unroll
        for (int mt = 0; mt < 4; ++mt)
            acc[mt][nt] = (f32x4){bv, bv, bv, bv};
    }
    #pragma unroll
    for (int ks = 0; ks < 2; ++ks) {
        #pragma unroll
        for (int mt = 0; mt < 4; ++mt) {
            int row = rowbase + mt * 16 + l16;
            bf16x8 af = *(const bf16x8*)(ygn + (size_t)row * 2048 + h * 64 + ks * 32 + quad * 8);
            #pragma unroll
            for (int nt = 0; nt < 4; ++nt)
                acc[mt][nt] = MFMA(af, bfr[nt][ks], acc[mt][nt]);
        }
    }
    #pragma unroll
    for (int mt = 0; mt < 4; ++mt)
        #pragma unroll
        for (int nt = 0; nt < 4; ++nt)
            #pragma unroll
            for (int r = 0; r < 4; ++r) {
                int row = rowbase + mt * 16 + quad * 4 + r;
                out[(size_t)row * 2048 + h * 64 + nt * 16 + l16] = acc[mt][nt][r];
            }
}

extern "C" void kernel_launch(void* const* d_in, const int* in_sizes, int n_in,
                              void* d_out, int out_size, void* d_ws, size_t ws_size,
                              hipStream_t stream) {
    const float* hs_ab   = (const float*)d_in[0];
    const float* hs_g    = (const float*)d_in[1];
    const float* qst     = (const float*)d_in[2];
    const float* kst     = (const float*)d_in[3];
    const float* vst     = (const float*)d_in[4];
    const float* dt_w    = (const float*)d_in[5];
    const float* dt_b    = (const float*)d_in[6];
    const float* g_w     = (const float*)d_in[7];
    const float* g_b     = (const float*)d_in[8];
    const float* A_log   = (const float*)d_in[9];
    const float* dt_bias = (const float*)d_in[10];
    const float* norm_w  = (const float*)d_in[11];
    const float* o_w     = (const float*)d_in[12];
    const float* o_b     = (const float*)d_in[13];
    float* out = (float*)d_out;

    float* ws = (float*)d_ws;
    size_t off = 0;
    float* dt_ws  = ws + off; off += (size_t)BATCH * SEQ * NH;
    float* g_ws   = ws + off; off += (size_t)BATCH * SEQ * NH;
    float* invC   = ws + off; off += (size_t)BATCH * SEQ * NH;
    float* invB   = ws + off; off += (size_t)BATCH * SEQ * NH;
    float* cumc   = ws + off; off += (size_t)NBCH * CHUNK;
    float* wvc    = ws + off; off += (size_t)NBCH * CHUNK;
    float* dtc    = ws + off; off += (size_t)NBCH * CHUNK;
    float* cd_ws  = ws + off; off += (size_t)NBCH;
    float* sp     = ws + off; off += (size_t)NBCH * 2 * 4096;
    float* Hp     = ws + off; off += (size_t)NBCH * 4096;

    short* ygb = (short*)sp;
    short* ygn = (short*)sp + (size_t)BATCH * SEQ * NH * 64;

    k_proj<<<2 * (BATCH * SEQ / 32), 256, 0, stream>>>(hs_ab, hs_g, dt_w, dt_b,
                                                       g_w, g_b, dt_bias, dt_ws, g_ws);
    k_norms<<<BATCH * SEQ * NH / 4, 256, 0, stream>>>(qst, kst, invC, invB);
    k_cumsum<<<NBCH, 256, 0, stream>>>(dt_ws, A_log, cumc, wvc, dtc, cd_ws);
    k_states<<<NBCH * 2, 256, 0, stream>>>(kst, vst, invB, wvc, sp);
    k_scan<<<BATCH * NH * 4096 / 256, 256, 0, stream>>>(sp, cd_ws, Hp);
    k_intra<<<NBCH, 256, 0, stream>>>(qst, kst, vst, invC, invB,
                                      cumc, dtc, Hp, ygb);
    k_gate<<<BATCH * SEQ, 256, 0, stream>>>(ygb, g_ws, norm_w, ygn);
    k_oproj<<<32 * (BATCH * SEQ / 256), 256, 0, stream>>>(ygn, o_w, o_b, out);
}